// Round 5
// baseline (118.925 us; speedup 1.0000x reference)
//
// v5: k_weights with prefetch distance 2 (xa/xb/xc rotation) to cover the
// ~900-cycle x-read latency; everything else identical to v4.
#include <hip/hip_runtime.h>

#define T 8
#define C 512
#define HW 196
#define NSEG 16                  // n
#define NT (NSEG * T)            // 128
#define NCOL (NT * HW)           // 25088 (nt, hw) columns
#define B_TOT (NSEG * HW)        // 3136
#define NH 4
#define KK 5
#define NO 20                    // NH*KK
#define S_SPLIT 8                // channel chunks = waves per block
#define CCH (C / S_SPLIT)        // 64 channels per chunk
#define COLS 64                  // columns per k_weights block (= lanes)

// ---------------------------------------------------------------------------
// Kernel 1: fused logits + LDS chunk-reduction + softmax -> weights.
// Grid 392 x 512. Wave w = channel chunk w (W via s_load, readfirstlane-
// pinned). Distance-2 software pipeline on the x loads: iteration i
// consumes buffer A, holds B (i+1) in flight, issues C (i+2).
// ---------------------------------------------------------------------------
__global__ __launch_bounds__(512, 4) void k_weights(const float* __restrict__ x,
                                                    const float* __restrict__ W,
                                                    float* __restrict__ wgt) {
    __shared__ float plds[S_SPLIT][NO][COLS];   // 40960 B

    const int tid  = threadIdx.x;
    const int lane = tid & 63;                  // column within tile
    const int sch  = tid >> 6;                  // wave index = channel chunk
    const int cbase = __builtin_amdgcn_readfirstlane(sch * CCH);  // SGPR

    const int idx = blockIdx.x * COLS + lane;   // flattened (nt, hw)
    const int nt  = idx / HW;
    const int hw  = idx - nt * HW;

    const float* xp = x + ((size_t)nt * C + cbase) * HW + hw;
    const float* Wb = W + cbase;                // wave-uniform base -> s_load

    float acc[NO];
#pragma unroll
    for (int o = 0; o < NO; ++o) acc[o] = 0.f;

    // software pipeline, distance 2: xa = current, xb = +8, xc = +16 in flight
    float xa[8], xb[8], xc[8];
#pragma unroll
    for (int u = 0; u < 8; ++u) xa[u] = xp[u * HW];
#pragma unroll
    for (int u = 0; u < 8; ++u) xb[u] = xp[(8 + u) * HW];

#pragma unroll
    for (int c0 = 0; c0 < CCH; c0 += 8) {
        if (c0 + 16 < CCH) {
#pragma unroll
            for (int u = 0; u < 8; ++u) xc[u] = xp[(c0 + 16 + u) * HW];
        }
        const float* wr = Wb + c0;              // wave-uniform
#pragma unroll
        for (int o = 0; o < NO; ++o) {
#pragma unroll
            for (int u = 0; u < 8; ++u)
                acc[o] = fmaf(xa[u], wr[o * C + u], acc[o]);
        }
#pragma unroll
        for (int u = 0; u < 8; ++u) { xa[u] = xb[u]; xb[u] = xc[u]; }
    }

    // partials: lane-consecutive -> 2-way bank aliasing max (free on CDNA4)
#pragma unroll
    for (int o = 0; o < NO; ++o) plds[sch][o][lane] = acc[o];
    __syncthreads();

    // reduce over chunks (same s-order as before -> identical numerics),
    // softmax over 5 taps. 256 threads: (col 0..63) x (head 0..3).
    if (tid < COLS * NH) {
        const int col  = tid & 63;
        const int h    = tid >> 6;
        const int idx2 = blockIdx.x * COLS + col;
        const int nt2  = idx2 / HW;
        const int hw2  = idx2 - nt2 * HW;
        const int t    = nt2 & (T - 1);
        const int n    = nt2 / T;
        const int b    = n * HW + hw2;

        float lg[KK];
#pragma unroll
        for (int k = 0; k < KK; ++k) {
            float sm = 0.f;
#pragma unroll
            for (int s2 = 0; s2 < S_SPLIT; ++s2)
                sm += plds[s2][h * KK + k][col];
            lg[k] = sm;
        }

        float m = lg[0];
#pragma unroll
        for (int k = 1; k < KK; ++k) m = fmaxf(m, lg[k]);
        float e[KK];
        float sum = 0.f;
#pragma unroll
        for (int k = 0; k < KK; ++k) {
            e[k] = __expf(lg[k] - m);
            sum += e[k];
        }
        const float r = 1.f / sum;
#pragma unroll
        for (int k = 0; k < KK; ++k)
            wgt[((size_t)((t * NH + h) * KK + k)) * B_TOT + b] = e[k] * r;
    }
}

// ---------------------------------------------------------------------------
// Kernel 2: causal dynamic conv, one thread per (n, c, hw). Unchanged —
// at its ~8 µs write floor (x re-read hits L3, out write is HBM-bound).
// ---------------------------------------------------------------------------
__global__ __launch_bounds__(256) void k_conv(const float* __restrict__ x,
                                              const float* __restrict__ wgt,
                                              float* __restrict__ out) {
    const int idx = blockIdx.x * 256 + threadIdx.x;  // < 16*512*196
    const int hw  = idx % HW;
    const int t1  = idx / HW;          // n*C + c
    const int c   = t1 % C;
    const int n   = t1 / C;
    const int h   = c >> 7;            // head
    const int b   = n * HW + hw;

    float w[T][KK];
#pragma unroll
    for (int t = 0; t < T; ++t)
#pragma unroll
        for (int k = 0; k < KK; ++k)
            w[t][k] = wgt[((size_t)((t * NH + h) * KK + k)) * B_TOT + b];

    const size_t base = ((size_t)(n * T) * C + c) * HW + hw;
    float xv[T];
#pragma unroll
    for (int t = 0; t < T; ++t) xv[t] = x[base + (size_t)t * C * HW];

#pragma unroll
    for (int t = 0; t < T; ++t) {
        float acc = 0.f;
#pragma unroll
        for (int k = 0; k < KK; ++k) {
            const int j = t + k - 4;   // causal, zero-padded left
            if (j >= 0) acc = fmaf(w[t][k], xv[j], acc);
        }
        out[base + (size_t)t * C * HW] = acc;
    }
}

// ---------------------------------------------------------------------------
extern "C" void kernel_launch(void* const* d_in, const int* in_sizes, int n_in,
                              void* d_out, int out_size, void* d_ws, size_t ws_size,
                              hipStream_t stream) {
    const float* x = (const float*)d_in[0];   // (128, 512, 14, 14)
    const float* W = (const float*)d_in[1];   // (20, 512)
    float* out = (float*)d_out;               // (128, 512, 14, 14)

    float* wgt = (float*)d_ws;                // 160 * 3136 floats = 2 MB

    k_weights<<<dim3(NCOL / COLS), 512, 0, stream>>>(x, W, wgt);
    k_conv<<<dim3((NSEG * C * HW) / 256), 256, 0, stream>>>(x, wgt, out);
}